// Round 3
// baseline (597.075 us; speedup 1.0000x reference)
//
#include <hip/hip_runtime.h>

// Problem constants (from reference module)
constexpr int T    = 8;
constexpr int ROWS = 100000;
constexpr int D    = 128;     // embedding dim
constexpr int B    = 8192;    // bags per table
constexpr int BAGS = T * B;   // 65536 total bags
constexpr int WAVES_PER_BLOCK = 4;   // 256 threads

typedef float v2f __attribute__((ext_vector_type(2)));  // native vector: ok for nontemporal builtin

// One bag per 64-lane wave. Lane L owns columns [2L, 2L+2) as v2f.
// Row load: 64 lanes x 8B = 512B = one full row per instruction, with a
// wave-uniform (SGPR) row base -> saddr-form global_load_dwordx2, zero
// per-load VALU address math, 32 fully independent loads in flight.
__global__ __launch_bounds__(256) void emb_bag_pool_kernel(
    const int*   __restrict__ indices,   // [N] int32
    const int*   __restrict__ offsets,   // [T*B+1] int32 (CSR)
    const float* __restrict__ weights,   // [T*ROWS, D] fp32, tables concatenated
    float*       __restrict__ out)       // [B, T*D] fp32
{
    const int lane = threadIdx.x & 63;
    const int seg  = blockIdx.x * WAVES_PER_BLOCK + (threadIdx.x >> 6);
    if (seg >= BAGS) return;

    const int t = seg >> 13;        // seg / B   (B = 8192 = 2^13)
    const int b = seg & (B - 1);    // seg % B

    // Wave-uniform bag bounds (same address in every lane -> one fetch).
    const int start = __builtin_amdgcn_readfirstlane(offsets[seg]);
    const int end   = __builtin_amdgcn_readfirstlane(offsets[seg + 1]);
    const int len   = end - start;

    const float* tbase = weights + (size_t)t * (size_t)ROWS * (size_t)D;

    v2f acc = {0.f, 0.f};

    if (len == 32) {
        // Fast path: the workload has uniform bag length 32.
        // One coalesced load of all 32 indices, distributed via readlane.
        const int vidx = (lane < 32) ? indices[start + lane] : 0;

        #pragma unroll
        for (int r = 0; r < 32; ++r) {
            const int row = __builtin_amdgcn_readlane(vidx, r);   // SGPR
            const v2f* wr = (const v2f*)(tbase + (size_t)row * D);
            const v2f v = wr[lane];                               // saddr + lane*8
            acc += v;
        }
    } else {
        for (int r = 0; r < len; ++r) {
            const int row = __builtin_amdgcn_readfirstlane(indices[start + r]);
            const v2f* wr = (const v2f*)(tbase + (size_t)row * D);
            const v2f v = wr[lane];
            acc += v;
        }
    }

    // out[b, t*D + 2*lane .. +2): 64 lanes x v2f = 512B contiguous.
    // Non-temporal: write-once output, keep L2/L3 for the weights table.
    v2f* orow = (v2f*)(out + (size_t)b * (size_t)(T * D) + (size_t)t * D);
    __builtin_nontemporal_store(acc, orow + lane);
}

extern "C" void kernel_launch(void* const* d_in, const int* in_sizes, int n_in,
                              void* d_out, int out_size, void* d_ws, size_t ws_size,
                              hipStream_t stream) {
    const int*   indices = (const int*)d_in[0];   // [N]
    const int*   offsets = (const int*)d_in[1];   // [T*B+1]
    const float* weights = (const float*)d_in[2]; // [T*ROWS*D]
    float*       out     = (float*)d_out;         // [B*T*D]

    const int grid = BAGS / WAVES_PER_BLOCK;      // 16384 blocks x 256 threads
    emb_bag_pool_kernel<<<grid, 256, 0, stream>>>(indices, offsets, weights, out);
}